// Round 14
// baseline (660.980 us; speedup 1.0000x reference)
//
#include <hip/hip_runtime.h>
#include <cstdint>

// FNet block on MI355X.
//   attn = Re(FFT2(x)) via bf16 MFMA matmuls + two-axis symmetry:
//     xfold: xb = bf16(x); xc[s']=x[s']+x[4096-s'], xs[s']=x[s']-x[4096-s']
//            (s'=1..2047; xc[0]=x[0], xc[2048]=x[2048], xs=0 there; pad
//            rows 2049..2175 zeroed). Fold-before-transform: the s-fold
//            commutes with the d-axis DFT, so fold x in fp32 (exact).
//     GEMM1 (z=0/1): U = xc @ C_D^T, V = xs @ S_D^T, epilogue packs directly
//            into BtUVf [b][d][s'] (s'-stride 2176). M=17408, N=512, K=768.
//     GEMM_uv (fused, z=0..15): u (cos) / v (sin), M=2176, N=512, K=2176
//     combine_ln: quadrant-combine u+-v (bf16), + xb residual (bf16),
//            fused row-LayerNorm -> out1 bf16
//   GEMM3: H = gelu(out1 @ W1 + b1)       (M=32768, N=3072, K=768)  [fast tanh-gelu]
//   GEMM4: y2 = H @ W2 + b2 + out1        (M=32768, N=768, K=3072)
//   LN2 in-place on d_out.
//
// GEMM core (unchanged from rounds 9-13, verified): 128x128 tile, BK=64, 4 waves,
// single 32 KiB LDS buffer, 2 barriers/K-tile, T2 swizzle (0 bank conflicts),
// gload_lds 16B staging, XCD-gather 1D grid + N-group decode (round 13).

typedef __attribute__((ext_vector_type(8))) short short8;
typedef __attribute__((ext_vector_type(4))) float f32x4;

__device__ __forceinline__ unsigned short f2b(float f) {
  union { float f; uint32_t u; } c; c.f = f;
  uint32_t u = c.u;
  u += 0x7FFFu + ((u >> 16) & 1u);   // round-to-nearest-even
  return (unsigned short)(u >> 16);
}
__device__ __forceinline__ float b2f(unsigned short h) {
  union { uint32_t u; float f; } c; c.u = ((uint32_t)h) << 16;
  return c.f;
}

// fast GELU (tanh form), ~9 VALU. max |err vs exact erf-gelu| ~3e-3.
__device__ __forceinline__ float gelu_fast(float x) {
  float x2 = x * x;
  float inner = x * fmaf(x2, 0.0356774081f, 0.7978845608f);
  float zz = fminf(inner * 2.885390082f, 80.0f);   // exp2 arg = 2*inner*log2(e)
  float E, r;
  asm("v_exp_f32 %0, %1" : "=v"(E) : "v"(zz));
  float den = E + 1.0f;
  asm("v_rcp_f32 %0, %1" : "=v"(r) : "v"(den));
  return x * E * r;
}

// ---------------------------------------------------------------------------
// xfold: xb = bf16(x) for all 4096 rows; xc/xs = folded rows (2176, padded).
// Block (k, b), k in 0..2048. Rows k and 4096-k handled together.
// ---------------------------------------------------------------------------
__global__ __launch_bounds__(256) void xfold(
    const float* __restrict__ x, unsigned short* __restrict__ xb,
    unsigned short* __restrict__ xc, unsigned short* __restrict__ xs) {
  const int k = blockIdx.x;            // 0..2048
  const int b = blockIdx.y;            // 0..7
  const long xbase = (long)b * 4096 * 768;
  const long cbase = (long)b * 2176 * 768;
  const int t = threadIdx.x;
#pragma unroll
  for (int it = 0; it < 3; ++it) {
    const int c = t + it * 256;
    const float a = x[xbase + (long)k * 768 + c];
    xb[xbase + (long)k * 768 + c] = f2b(a);
    if (k == 0 || k == 2048) {
      xc[cbase + (long)k * 768 + c] = f2b(a);
      xs[cbase + (long)k * 768 + c] = 0;
    } else {
      const float bb = x[xbase + (long)(4096 - k) * 768 + c];
      xb[xbase + (long)(4096 - k) * 768 + c] = f2b(bb);
      xc[cbase + (long)k * 768 + c] = f2b(a + bb);
      xs[cbase + (long)k * 768 + c] = f2b(a - bb);
    }
    if (k >= 1 && k <= 127) {          // zero pad rows 2049..2175
      xc[cbase + (long)(2048 + k) * 768 + c] = 0;
      xs[cbase + (long)(2048 + k) * 768 + c] = 0;
    }
  }
}

// Bt1: (1024 x 768). Row j<512: cos(2*pi*j*n/768); row j>=512: sin(2*pi*(j-512)*n/768).
__global__ __launch_bounds__(256) void fill_bt1(unsigned short* __restrict__ Bt1) {
  int i = blockIdx.x * 256 + threadIdx.x;          // < 1024*768
  int j = i / 768;
  int n = i - j * 768;
  int jj = j & 511;
  int m = (jj * n) % 768;
  float ang = (float)m * (6.283185307179586f / 768.0f);
  Bt1[i] = f2b((j < 512) ? cosf(ang) : sinf(ang));
}

// Au[k][s'] = cos(2*pi*k*s'/4096), Av[k][s'] = sin(...), k,s' in 0..2175.
// (s' >= 2049 multiplies zero-padded data; value irrelevant.)
__global__ __launch_bounds__(256) void fill_auv(
    unsigned short* __restrict__ Au, unsigned short* __restrict__ Av) {
  long i = (long)blockIdx.x * 256 + threadIdx.x;   // < 2176*2176
  if (i >= 2176L * 2176L) return;
  int k = (int)(i / 2176);
  int s = (int)(i - (long)k * 2176);
  int mm = (k * s) & 4095;
  float ang = (float)mm * (6.283185307179586f / 4096.0f);
  Au[i] = f2b(cosf(ang));
  Av[i] = f2b(sinf(ang));
}

// out[c][r] = bf16(in[r][c]); R,C multiples of 32  (for W1, W2)
__global__ __launch_bounds__(256) void transpose_f32_to_bf16(
    const float* __restrict__ in, unsigned short* __restrict__ out, int R, int C) {
  __shared__ float tile[32][33];
  const int c0 = blockIdx.x * 32;
  const int r0 = blockIdx.y * 32;
  const int tx = threadIdx.x & 31;
  const int ty = threadIdx.x >> 5;   // 0..7
#pragma unroll
  for (int i = ty; i < 32; i += 8)
    tile[i][tx] = in[(long)(r0 + i) * C + c0 + tx];
  __syncthreads();
#pragma unroll
  for (int i = ty; i < 32; i += 8)
    out[(long)(c0 + i) * R + r0 + tx] = f2b(tile[tx][i]);
}

// ---------------------------------------------------------------------------
// GEMM128: C = A (MxK row-major bf16) @ Bt^T (Bt NxK row-major bf16)
// 128x128 tile, BK=64, 256 threads (4 waves, 2x2), per-wave 64x64, acc[4][4].
// Single 32 KiB LDS buffer, 2 syncthreads/K-tile. T2 swizzle.
// 1D grid, XCD-gather remap (grid % 8 == 0) + N-GROUP decode:
//   l = (p%8)*(total/8)+p/8;
//   byg = l%NYG; bx = (l/NYG)%NX; g = (l/(NYG*NX))%NG; zz = l/(NYG*NX*NG);
//   by = g*NYG + byg.
// z>=zSplit switches operand set (A2p, Bt2p, outB2) for EPI 0 and 1.
// Epilogues:
//   0 = transpose-pack: dst[(b*512+col)*2176 + s'], b=r/2176, s'=r%2176
//       (GEMM1 -> BtUVf U/V halves, z-switched)
//   1 = bf16 z-batched store (GEMM_u / GEMM_v, z-switched)
//   2 = +bias, fast gelu, bf16 (GEMM3->H)
//   3 = +bias +bf16 residual, fp32 (GEMM4->y2)
// M,N multiples of 128; K multiple of 64.
// ---------------------------------------------------------------------------

template <int EPI>
__global__ __launch_bounds__(256, 3) void gemm128(
    const unsigned short* __restrict__ A, const unsigned short* __restrict__ Bt,
    const unsigned short* __restrict__ A2p, const unsigned short* __restrict__ Bt2p,
    int K, int lda, int ldb, long bBatch, long oBatch, int zSplit,
    int NX, int NYG, int NG,
    float* __restrict__ outF,
    unsigned short* __restrict__ outB, unsigned short* __restrict__ outB2,
    const float* __restrict__ bias, const unsigned short* __restrict__ residB,
    int ldOut) {
  __shared__ __align__(16) unsigned short As[128 * 64];   // 16 KB
  __shared__ __align__(16) unsigned short Bs[128 * 64];   // 16 KB

  const int tid = threadIdx.x;
  const int lane = tid & 63;
  const int wave = tid >> 6;         // 0..3
  const int wr = wave >> 1;          // 0..1
  const int wc = wave & 1;           // 0..1

  // ---- XCD-gather remap + N-group decode ----
  const int p = (int)blockIdx.x;
  const int l = (p & 7) * ((int)gridDim.x >> 3) + (p >> 3);
  int rem = l;
  const int byg = rem % NYG; rem /= NYG;
  const int bx  = rem % NX;  rem /= NX;
  const int g   = rem % NG;  rem /= NG;
  int zz = rem;
  const int by = g * NYG + byg;

  const unsigned short* Ax = A;
  const unsigned short* Bx = Bt;
  unsigned short* oB = outB;
  if ((EPI == 0 || EPI == 1) && zz >= zSplit) { Ax = A2p; Bx = Bt2p; oB = outB2; zz -= zSplit; }

  const unsigned short* Ab = Ax + (long)bx * 128 * lda;
  const unsigned short* Bb = Bx + (long)zz * bBatch + (long)by * 128 * ldb;

  const int NT = K >> 6;             // #K-tiles

  // Staging: linear LDS dest, T2 swizzle pre-applied to per-lane GLOBAL column.
  const int srow = lane >> 3;                      // 0..7
  const int scolE = ((lane & 7) ^ srow) << 3;      // pre-swizzled col (elems)

  const int fr = lane & 15;          // frag row within 16
  const int fkB = (lane >> 4) << 4;  // byte k-offset within 32-k half (0,16,32,48)
  const int fxor = (lane & 7) << 4;  // T2 swizzle XOR (row&7 == lane&7 for frag rows)

  f32x4 acc[4][4] = {};

  for (int t = 0; t < NT; ++t) {
    // ---- stage tile t: 16 chunks of 8 rows; wave w does chunks i*4+w ----
#pragma unroll
    for (int i_ = 0; i_ < 4; ++i_) {
      const int chunk = i_ * 4 + wave;             // wave-uniform
      const int row = chunk * 8 + srow;
      __builtin_amdgcn_global_load_lds(
          (const __attribute__((address_space(1))) void*)(Ab + (long)row * lda + (long)t * 64 + scolE),
          (__attribute__((address_space(3))) void*)(As + chunk * 512), 16, 0, 0);
      __builtin_amdgcn_global_load_lds(
          (const __attribute__((address_space(1))) void*)(Bb + (long)row * ldb + (long)t * 64 + scolE),
          (__attribute__((address_space(3))) void*)(Bs + chunk * 512), 16, 0, 0);
    }
    __syncthreads();   // drains vmcnt (gload_lds) — data visible to all waves

    const char* Ap = reinterpret_cast<const char*>(As);
    const char* Bp = reinterpret_cast<const char*>(Bs);
#pragma unroll
    for (int ks = 0; ks < 2; ++ks) {
      short8 af[4], bf[4];
#pragma unroll
      for (int mf = 0; mf < 4; ++mf) {
        const int row = wr * 64 + mf * 16 + fr;
        af[mf] = *reinterpret_cast<const short8*>(Ap + ((row * 128 + ks * 64 + fkB) ^ fxor));
      }
#pragma unroll
      for (int nf = 0; nf < 4; ++nf) {
        const int row = wc * 64 + nf * 16 + fr;
        bf[nf] = *reinterpret_cast<const short8*>(Bp + ((row * 128 + ks * 64 + fkB) ^ fxor));
      }
#pragma unroll
      for (int mf = 0; mf < 4; ++mf)
#pragma unroll
        for (int nf = 0; nf < 4; ++nf)
          acc[mf][nf] = __builtin_amdgcn_mfma_f32_16x16x32_bf16(
              af[mf], bf[nf], acc[mf][nf], 0, 0, 0);
    }
    __syncthreads();   // all waves done reading before next stage overwrites
  }

  // Epilogue. C/D layout: col = lane&15, row = (lane>>4)*4 + reg  [m89/m91]
  const long rowBase = (long)bx * 128 + wr * 64 + ((lane >> 4) << 2);
  const int colBase = by * 128 + wc * 64 + (lane & 15);
#pragma unroll
  for (int mf = 0; mf < 4; ++mf) {
#pragma unroll
    for (int nf = 0; nf < 4; ++nf) {
      const int col = colBase + nf * 16;
#pragma unroll
      for (int i = 0; i < 4; ++i) {
        const long r = rowBase + mf * 16 + i;
        float vv = acc[mf][nf][i];
        if constexpr (EPI == 0) {
          // pack: b = r/2176, s' = r%2176; dst = (b*512+col)*2176 + s'
          const int rr = (int)r;
          const int bz = rr / 2176;
          const int sp = rr - bz * 2176;
          oB[((long)(bz * 512 + col)) * 2176 + sp] = f2b(vv);
        } else if constexpr (EPI == 1) {
          oB[(long)zz * oBatch + r * (long)ldOut + col] = f2b(vv);
        } else if constexpr (EPI == 2) {
          outB[r * (long)ldOut + col] = f2b(gelu_fast(vv + bias[col]));
        } else {
          const long idx = r * (long)ldOut + col;
          outF[idx] = vv + bias[col] + b2f(residB[idx]);
        }
      }
    }
  }
}

// ---------------------------------------------------------------------------
// combine_ln: quadrant combine (bf16 u,v) + xb residual (bf16) + row LayerNorm.
// Block (k,z) owns FULL rows k and 4096-k; writes out1 bf16 directly.
// u/v row stride is 2176 (padded M of GEMM_uv).
// ---------------------------------------------------------------------------
__global__ __launch_bounds__(256) void combine_ln(
    const unsigned short* __restrict__ u, const unsigned short* __restrict__ v,
    const unsigned short* __restrict__ xb, const float* __restrict__ gamma,
    const float* __restrict__ beta, unsigned short* __restrict__ o1b) {
  const int k = blockIdx.x;            // 0..2048
  const int z = blockIdx.y;            // 0..7
  const long ub = ((long)z * 2176 + k) * 512;
  const long base = (long)z * 4096L * 768;
  const long rowA = base + (long)k * 768;
  const long rowB = base + (long)(4096 - k) * 768;
  const bool doRowB = (k != 0) && (k != 2048);
  const int t = threadIdx.x;

  float vA0[2], vA1[2], vB0[2], vB1[2];
  float sA = 0.f, qA = 0.f, sB = 0.f, qB = 0.f;
#pragma unroll
  for (int it = 0; it < 2; ++it) {
    const int d = t + it * 256;
    if (d <= 384) {
      const float uu = b2f(u[ub + d]);
      const float vv = b2f(v[ub + d]);
      const float a1 = uu - vv;
      const float a2 = uu + vv;
      const int dd = 768 - d;
      const bool colB = (d != 0) && (d != 384);
      float va = a1 + b2f(xb[rowA + d]);
      vA0[it] = va; sA += va; qA += va * va;
      if (colB) { float w = a2 + b2f(xb[rowA + dd]); vA1[it] = w; sA += w; qA += w * w; }
      if (doRowB) {
        float wb = a2 + b2f(xb[rowB + d]);
        vB0[it] = wb; sB += wb; qB += wb * wb;
        if (colB) { float w2 = a1 + b2f(xb[rowB + dd]); vB1[it] = w2; sB += w2; qB += w2 * w2; }
      }
    }
  }
#pragma unroll
  for (int off = 32; off > 0; off >>= 1) {
    sA += __shfl_down(sA, off, 64); qA += __shfl_down(qA, off, 64);
    sB += __shfl_down(sB, off, 64); qB += __shfl_down(qB, off, 64);
  }
  __shared__ float red[4][4];
  if ((t & 63) == 0) {
    red[t >> 6][0] = sA; red[t >> 6][1] = qA;
    red[t >> 6][2] = sB; red[t >> 6][3] = qB;
  }
  __syncthreads();
  const float SA = red[0][0] + red[1][0] + red[2][0] + red[3][0];
  const float QA = red[0][1] + red[1][1] + red[2][1] + red[3][1];
  const float SB = red[0][2] + red[1][2] + red[2][2] + red[3][2];
  const float QB = red[0][3] + red[1][3] + red[2][3] + red[3][3];
  const float muA = SA * (1.0f / 768.0f);
  const float rsA = rsqrtf(QA * (1.0f / 768.0f) - muA * muA + 1e-6f);
  const float muB = SB * (1.0f / 768.0f);
  const float rsB = rsqrtf(QB * (1.0f / 768.0f) - muB * muB + 1e-6f);

#pragma unroll
  for (int it = 0; it < 2; ++it) {
    const int d = t + it * 256;
    if (d <= 384) {
      const int dd = 768 - d;
      const bool colB = (d != 0) && (d != 384);
      const float g0 = gamma[d], b0 = beta[d];
      o1b[rowA + d] = f2b((vA0[it] - muA) * rsA * g0 + b0);
      if (colB) o1b[rowA + dd] = f2b((vA1[it] - muA) * rsA * gamma[dd] + beta[dd]);
      if (doRowB) {
        o1b[rowB + d] = f2b((vB0[it] - muB) * rsB * g0 + b0);
        if (colB) o1b[rowB + dd] = f2b((vB1[it] - muB) * rsB * gamma[dd] + beta[dd]);
      }
    }
  }
}

// ---------------------------------------------------------------------------
// Row LayerNorm over D=768 (fp32 in/out, used for LN2 in-place).
// ---------------------------------------------------------------------------
__global__ __launch_bounds__(256) void ln_row_f32(
    const float* __restrict__ in, const float* __restrict__ gamma,
    const float* __restrict__ beta, float* __restrict__ outF) {
  const long row = blockIdx.x;
  const float* p = in + row * 768;
  const int t = threadIdx.x;
  const float v0 = p[t], v1 = p[t + 256], v2 = p[t + 512];
  float s = v0 + v1 + v2;
  float q = v0 * v0 + v1 * v1 + v2 * v2;
#pragma unroll
  for (int off = 32; off > 0; off >>= 1) {
    s += __shfl_down(s, off, 64);
    q += __shfl_down(q, off, 64);
  }
  __shared__ float ss[4], sq[4];
  if ((t & 63) == 0) { ss[t >> 6] = s; sq[t >> 6] = q; }
  __syncthreads();
  const float S = ss[0] + ss[1] + ss[2] + ss[3];
  const float Q = sq[0] + sq[1] + sq[2] + sq[3];
  const float mu = S * (1.0f / 768.0f);
  const float var = Q * (1.0f / 768.0f) - mu * mu;
  const float rs = rsqrtf(var + 1e-6f);
  outF[row * 768 + t]       = (v0 - mu) * rs * gamma[t] + beta[t];
  outF[row * 768 + t + 256] = (v1 - mu) * rs * gamma[t + 256] + beta[t + 256];
  outF[row * 768 + t + 512] = (v2 - mu) * rs * gamma[t + 512] + beta[t + 512];
}

// ---------------------------------------------------------------------------

extern "C" void kernel_launch(void* const* d_in, const int* in_sizes, int n_in,
                              void* d_out, int out_size, void* d_ws, size_t ws_size,
                              hipStream_t stream) {
  const float* x   = (const float*)d_in[0];   // (8,4096,768)
  const float* W1  = (const float*)d_in[1];   // (768,3072)
  const float* b1  = (const float*)d_in[2];   // (3072)
  const float* W2  = (const float*)d_in[3];   // (3072,768)
  const float* b2  = (const float*)d_in[4];   // (768)
  const float* g1  = (const float*)d_in[5];
  const float* be1 = (const float*)d_in[6];
  const float* g2  = (const float*)d_in[7];
  const float* be2 = (const float*)d_in[8];
  float* out = (float*)d_out;                 // fp32, also y2 scratch

  char* ws = (char*)d_ws;
  unsigned short* xb   = (unsigned short*)(ws + 0L);           //  50,331,648 (live until combine_ln)
  unsigned short* Bt1  = (unsigned short*)(ws + 50331648L);    //   1,572,864
  unsigned short* Au   = (unsigned short*)(ws + 51904512L);    //   9,469,952 (2176x2176)
  unsigned short* Av   = (unsigned short*)(ws + 61374464L);    //   9,469,952
  unsigned short* xc   = (unsigned short*)(ws + 70844416L);    //  26,738,688 (8x2176x768)
  unsigned short* xs   = (unsigned short*)(ws + 97583104L);    //  26,738,688
  unsigned short* BtU  = (unsigned short*)(ws + 124321792L);   //  17,825,792 (8x512x2176)
  unsigned short* BtV  = (unsigned short*)(ws + 142147584L);   //  17,825,792 -> ends 159,973,376
  unsigned short* u_b  = (unsigned short*)(ws + 159973376L);   //  17,825,792 (8x2176x512)
  unsigned short* v_b  = (unsigned short*)(ws + 177799168L);   //  17,825,792 -> ends 195,624,960
  unsigned short* H    = (unsigned short*)(ws + 0L);           // 201,326,592 (aliases all above; dead by GEMM3)
  unsigned short* o1b  = (unsigned short*)(ws + 201326592L);   //  50,331,648
  unsigned short* W1t  = (unsigned short*)(ws + 251658240L);   //   4,718,592
  unsigned short* W2t  = (unsigned short*)(ws + 256376832L);   //   4,718,592
  // total ws needed: 261,095,424 bytes (~249 MiB)

  // --- prep ---
  xfold<<<dim3(2049, 8), 256, 0, stream>>>(x, xb, xc, xs);
  fill_bt1<<<3072, 256, 0, stream>>>(Bt1);
  fill_auv<<<18496, 256, 0, stream>>>(Au, Av);                  // ceil(2176*2176/256)
  transpose_f32_to_bf16<<<dim3(96, 24), 256, 0, stream>>>(W1, W1t, 768, 3072);
  transpose_f32_to_bf16<<<dim3(24, 96), 256, 0, stream>>>(W2, W2t, 3072, 768);

  // --- GEMM1 (z=0: U = xc@C_D^T; z=1: V = xs@S_D^T), packed into BtU/BtV;
  //     M=17408, N=512, K=768 -> 136x4x2 = 1088 blocks ---
  gemm128<0><<<1088, 256, 0, stream>>>(
      xc, Bt1, xs, Bt1 + 512 * 768, 768, 768, 768, 0L, 0L, 1, 136, 4, 1,
      nullptr, BtU, BtV, nullptr, nullptr, 0);

  // --- GEMM_uv fused (z<8: u -> u_b; z>=8: v -> v_b); M=2176, K=2176,
  //     17x4x16 = 1088 blocks, bf16 outputs ---
  gemm128<1><<<1088, 256, 0, stream>>>(
      Au, BtU, Av, BtV, 2176, 2176, 2176,
      512L * 2176L, 2176L * 512L, 8, 17, 4, 1,
      nullptr, u_b, v_b, nullptr, nullptr, 512);

  // --- combine quadrants + xb residual + LN1 -> out1 (bf16), fused ---
  combine_ln<<<dim3(2049, 8), 256, 0, stream>>>(u_b, v_b, xb, g1, be1, o1b);

  // --- GEMM3: H = gelu(out1 @ W1 + b1); NYG=12, NG=2 -> 256x12x2 = 6144 blocks ---
  gemm128<2><<<6144, 256, 0, stream>>>(
      o1b, W1t, nullptr, nullptr, 768, 768, 768, 0L, 0L, 999, 256, 12, 2,
      nullptr, H, nullptr, b1, nullptr, 3072);

  // --- GEMM4: y2 = H @ W2 + b2 + out1 -> d_out; 256x6 = 1536 blocks ---
  gemm128<3><<<1536, 256, 0, stream>>>(
      H, W2t, nullptr, nullptr, 3072, 3072, 3072, 0L, 0L, 999, 256, 6, 1,
      out, nullptr, nullptr, b2, o1b, 768);

  // --- LN2 in-place ---
  ln_row_f32<<<32768, 256, 0, stream>>>(out, g2, be2, out);
}

// Round 15
// 626.485 us; speedup vs baseline: 1.0551x; 1.0551x over previous
//
#include <hip/hip_runtime.h>
#include <cstdint>

// FNet block on MI355X.
//   attn = Re(FFT2(x)) via bf16 MFMA matmuls + two-axis symmetry:
//     xfold (vectorized): xb = bf16(x); xc[s']=x[s']+x[4096-s'], xs=x-x_mirror
//     GEMM1 (z=0/1): U = xc @ C_D^T, V = xs @ S_D^T, packed into BtU/BtV
//     GEMM_uv (fused, z=0..15): u (cos) / v (sin), M=2176, N=512, K=2176
//     combine_ln: quadrant-combine + xb residual + row-LayerNorm -> out1 bf16
//   GEMM3: H = gelu(out1 @ W1 + b1)   [fast tanh-gelu]
//   GEMM4: y2 = H @ W2 + b2 + out1, written bf16 IN-PLACE over o1b
//          (each thread reads resid[idx] then writes same idx - race-free)
//   LN2: bf16 y2 -> fp32 d_out (vectorized ushort4/float4).
//
// GEMM core (unchanged from rounds 9-14, verified): 128x128 tile, BK=64, 4 waves,
// single 32 KiB LDS buffer, 2 barriers/K-tile, T2 swizzle (0 bank conflicts),
// gload_lds 16B staging, XCD-gather 1D grid + N-group decode.

typedef __attribute__((ext_vector_type(8))) short short8;
typedef __attribute__((ext_vector_type(4))) float f32x4;

__device__ __forceinline__ unsigned short f2b(float f) {
  union { float f; uint32_t u; } c; c.f = f;
  uint32_t u = c.u;
  u += 0x7FFFu + ((u >> 16) & 1u);   // round-to-nearest-even
  return (unsigned short)(u >> 16);
}
__device__ __forceinline__ float b2f(unsigned short h) {
  union { uint32_t u; float f; } c; c.u = ((uint32_t)h) << 16;
  return c.f;
}

// fast GELU (tanh form), ~9 VALU. max |err vs exact erf-gelu| ~3e-3.
__device__ __forceinline__ float gelu_fast(float x) {
  float x2 = x * x;
  float inner = x * fmaf(x2, 0.0356774081f, 0.7978845608f);
  float zz = fminf(inner * 2.885390082f, 80.0f);   // exp2 arg = 2*inner*log2(e)
  float E, r;
  asm("v_exp_f32 %0, %1" : "=v"(E) : "v"(zz));
  float den = E + 1.0f;
  asm("v_rcp_f32 %0, %1" : "=v"(r) : "v"(den));
  return x * E * r;
}

// ---------------------------------------------------------------------------
// xfold (vectorized): xb = bf16(x) all rows; xc/xs = folded rows (2176, padded).
// Block (k, b), k in 0..2048; 192 threads, thread t covers cols 4t..4t+3.
// ---------------------------------------------------------------------------
__global__ __launch_bounds__(192) void xfold(
    const float* __restrict__ x, unsigned short* __restrict__ xb,
    unsigned short* __restrict__ xc, unsigned short* __restrict__ xs) {
  const int k = blockIdx.x;            // 0..2048
  const int b = blockIdx.y;            // 0..7
  const long xbase = (long)b * 4096 * 768;
  const long cbase = (long)b * 2176 * 768;
  const int t = threadIdx.x;           // 0..191

  const float4 a = reinterpret_cast<const float4*>(x + xbase + (long)k * 768)[t];
  const ushort4 ab = {f2b(a.x), f2b(a.y), f2b(a.z), f2b(a.w)};
  reinterpret_cast<ushort4*>(xb + xbase + (long)k * 768)[t] = ab;

  if (k == 0 || k == 2048) {
    reinterpret_cast<ushort4*>(xc + cbase + (long)k * 768)[t] = ab;
    reinterpret_cast<ushort4*>(xs + cbase + (long)k * 768)[t] = ushort4{0, 0, 0, 0};
  } else {
    const float4 bb = reinterpret_cast<const float4*>(x + xbase + (long)(4096 - k) * 768)[t];
    const ushort4 bbb = {f2b(bb.x), f2b(bb.y), f2b(bb.z), f2b(bb.w)};
    reinterpret_cast<ushort4*>(xb + xbase + (long)(4096 - k) * 768)[t] = bbb;
    const ushort4 cc = {f2b(a.x + bb.x), f2b(a.y + bb.y), f2b(a.z + bb.z), f2b(a.w + bb.w)};
    const ushort4 ssv = {f2b(a.x - bb.x), f2b(a.y - bb.y), f2b(a.z - bb.z), f2b(a.w - bb.w)};
    reinterpret_cast<ushort4*>(xc + cbase + (long)k * 768)[t] = cc;
    reinterpret_cast<ushort4*>(xs + cbase + (long)k * 768)[t] = ssv;
  }
  if (k >= 1 && k <= 127) {            // zero pad rows 2049..2175
    reinterpret_cast<ushort4*>(xc + cbase + (long)(2048 + k) * 768)[t] = ushort4{0, 0, 0, 0};
    reinterpret_cast<ushort4*>(xs + cbase + (long)(2048 + k) * 768)[t] = ushort4{0, 0, 0, 0};
  }
}

// Bt1: (1024 x 768). Row j<512: cos(2*pi*j*n/768); row j>=512: sin(2*pi*(j-512)*n/768).
__global__ __launch_bounds__(256) void fill_bt1(unsigned short* __restrict__ Bt1) {
  int i = blockIdx.x * 256 + threadIdx.x;          // < 1024*768
  int j = i / 768;
  int n = i - j * 768;
  int jj = j & 511;
  int m = (jj * n) % 768;
  float ang = (float)m * (6.283185307179586f / 768.0f);
  Bt1[i] = f2b((j < 512) ? cosf(ang) : sinf(ang));
}

// Au[k][s'] = cos(2*pi*k*s'/4096), Av[k][s'] = sin(...), k,s' in 0..2175.
__global__ __launch_bounds__(256) void fill_auv(
    unsigned short* __restrict__ Au, unsigned short* __restrict__ Av) {
  long i = (long)blockIdx.x * 256 + threadIdx.x;   // < 2176*2176
  if (i >= 2176L * 2176L) return;
  int k = (int)(i / 2176);
  int s = (int)(i - (long)k * 2176);
  int mm = (k * s) & 4095;
  float ang = (float)mm * (6.283185307179586f / 4096.0f);
  Au[i] = f2b(cosf(ang));
  Av[i] = f2b(sinf(ang));
}

// out[c][r] = bf16(in[r][c]); R,C multiples of 32  (for W1, W2)
__global__ __launch_bounds__(256) void transpose_f32_to_bf16(
    const float* __restrict__ in, unsigned short* __restrict__ out, int R, int C) {
  __shared__ float tile[32][33];
  const int c0 = blockIdx.x * 32;
  const int r0 = blockIdx.y * 32;
  const int tx = threadIdx.x & 31;
  const int ty = threadIdx.x >> 5;   // 0..7
#pragma unroll
  for (int i = ty; i < 32; i += 8)
    tile[i][tx] = in[(long)(r0 + i) * C + c0 + tx];
  __syncthreads();
#pragma unroll
  for (int i = ty; i < 32; i += 8)
    out[(long)(c0 + i) * R + r0 + tx] = f2b(tile[tx][i]);
}

// ---------------------------------------------------------------------------
// GEMM128: C = A (MxK row-major bf16) @ Bt^T (Bt NxK row-major bf16)
// 128x128 tile, BK=64, 256 threads (4 waves, 2x2), per-wave 64x64, acc[4][4].
// Single 32 KiB LDS buffer, 2 syncthreads/K-tile. T2 swizzle.
// 1D grid, XCD-gather remap (grid % 8 == 0) + N-GROUP decode:
//   l = (p%8)*(total/8)+p/8;
//   byg = l%NYG; bx = (l/NYG)%NX; g = (l/(NYG*NX))%NG; zz = l/(NYG*NX*NG);
//   by = g*NYG + byg.
// z>=zSplit switches operand set (A2p, Bt2p, outB2) for EPI 0 and 1.
// Epilogues:
//   0 = transpose-pack: dst[(b*512+col)*2176 + s'], b=r/2176, s'=r%2176
//   1 = bf16 z-batched store (GEMM_u / GEMM_v, z-switched)
//   2 = +bias, fast gelu, bf16 (GEMM3->H)
//   3 = +bias +bf16 resid, bf16 store IN-PLACE over residB (GEMM4->y2b)
// M,N multiples of 128; K multiple of 64.
// ---------------------------------------------------------------------------

template <int EPI>
__global__ __launch_bounds__(256, 3) void gemm128(
    const unsigned short* __restrict__ A, const unsigned short* __restrict__ Bt,
    const unsigned short* __restrict__ A2p, const unsigned short* __restrict__ Bt2p,
    int K, int lda, int ldb, long bBatch, long oBatch, int zSplit,
    int NX, int NYG, int NG,
    unsigned short* __restrict__ outB, unsigned short* __restrict__ outB2,
    const float* __restrict__ bias, const unsigned short* __restrict__ residB,
    int ldOut) {
  __shared__ __align__(16) unsigned short As[128 * 64];   // 16 KB
  __shared__ __align__(16) unsigned short Bs[128 * 64];   // 16 KB

  const int tid = threadIdx.x;
  const int lane = tid & 63;
  const int wave = tid >> 6;         // 0..3
  const int wr = wave >> 1;          // 0..1
  const int wc = wave & 1;           // 0..1

  // ---- XCD-gather remap + N-group decode ----
  const int p = (int)blockIdx.x;
  const int l = (p & 7) * ((int)gridDim.x >> 3) + (p >> 3);
  int rem = l;
  const int byg = rem % NYG; rem /= NYG;
  const int bx  = rem % NX;  rem /= NX;
  const int g   = rem % NG;  rem /= NG;
  int zz = rem;
  const int by = g * NYG + byg;

  const unsigned short* Ax = A;
  const unsigned short* Bx = Bt;
  unsigned short* oB = outB;
  if ((EPI == 0 || EPI == 1) && zz >= zSplit) { Ax = A2p; Bx = Bt2p; oB = outB2; zz -= zSplit; }

  const unsigned short* Ab = Ax + (long)bx * 128 * lda;
  const unsigned short* Bb = Bx + (long)zz * bBatch + (long)by * 128 * ldb;

  const int NT = K >> 6;             // #K-tiles

  // Staging: linear LDS dest, T2 swizzle pre-applied to per-lane GLOBAL column.
  const int srow = lane >> 3;                      // 0..7
  const int scolE = ((lane & 7) ^ srow) << 3;      // pre-swizzled col (elems)

  const int fr = lane & 15;          // frag row within 16
  const int fkB = (lane >> 4) << 4;  // byte k-offset within 32-k half (0,16,32,48)
  const int fxor = (lane & 7) << 4;  // T2 swizzle XOR (row&7 == lane&7 for frag rows)

  f32x4 acc[4][4] = {};

  for (int t = 0; t < NT; ++t) {
    // ---- stage tile t: 16 chunks of 8 rows; wave w does chunks i*4+w ----
#pragma unroll
    for (int i_ = 0; i_ < 4; ++i_) {
      const int chunk = i_ * 4 + wave;             // wave-uniform
      const int row = chunk * 8 + srow;
      __builtin_amdgcn_global_load_lds(
          (const __attribute__((address_space(1))) void*)(Ab + (long)row * lda + (long)t * 64 + scolE),
          (__attribute__((address_space(3))) void*)(As + chunk * 512), 16, 0, 0);
      __builtin_amdgcn_global_load_lds(
          (const __attribute__((address_space(1))) void*)(Bb + (long)row * ldb + (long)t * 64 + scolE),
          (__attribute__((address_space(3))) void*)(Bs + chunk * 512), 16, 0, 0);
    }
    __syncthreads();   // drains vmcnt (gload_lds) — data visible to all waves

    const char* Ap = reinterpret_cast<const char*>(As);
    const char* Bp = reinterpret_cast<const char*>(Bs);
#pragma unroll
    for (int ks = 0; ks < 2; ++ks) {
      short8 af[4], bf[4];
#pragma unroll
      for (int mf = 0; mf < 4; ++mf) {
        const int row = wr * 64 + mf * 16 + fr;
        af[mf] = *reinterpret_cast<const short8*>(Ap + ((row * 128 + ks * 64 + fkB) ^ fxor));
      }
#pragma unroll
      for (int nf = 0; nf < 4; ++nf) {
        const int row = wc * 64 + nf * 16 + fr;
        bf[nf] = *reinterpret_cast<const short8*>(Bp + ((row * 128 + ks * 64 + fkB) ^ fxor));
      }
#pragma unroll
      for (int mf = 0; mf < 4; ++mf)
#pragma unroll
        for (int nf = 0; nf < 4; ++nf)
          acc[mf][nf] = __builtin_amdgcn_mfma_f32_16x16x32_bf16(
              af[mf], bf[nf], acc[mf][nf], 0, 0, 0);
    }
    __syncthreads();   // all waves done reading before next stage overwrites
  }

  // Epilogue. C/D layout: col = lane&15, row = (lane>>4)*4 + reg  [m89/m91]
  const long rowBase = (long)bx * 128 + wr * 64 + ((lane >> 4) << 2);
  const int colBase = by * 128 + wc * 64 + (lane & 15);
#pragma unroll
  for (int mf = 0; mf < 4; ++mf) {
#pragma unroll
    for (int nf = 0; nf < 4; ++nf) {
      const int col = colBase + nf * 16;
#pragma unroll
      for (int i = 0; i < 4; ++i) {
        const long r = rowBase + mf * 16 + i;
        float vv = acc[mf][nf][i];
        if constexpr (EPI == 0) {
          // pack: b = r/2176, s' = r%2176; dst = (b*512+col)*2176 + s'
          const int rr = (int)r;
          const int bz = rr / 2176;
          const int sp = rr - bz * 2176;
          oB[((long)(bz * 512 + col)) * 2176 + sp] = f2b(vv);
        } else if constexpr (EPI == 1) {
          oB[(long)zz * oBatch + r * (long)ldOut + col] = f2b(vv);
        } else if constexpr (EPI == 2) {
          outB[r * (long)ldOut + col] = f2b(gelu_fast(vv + bias[col]));
        } else {
          // y2 bf16 in-place over residB: same thread reads then writes idx.
          const long idx = r * (long)ldOut + col;
          outB[idx] = f2b(vv + bias[col] + b2f(residB[idx]));
        }
      }
    }
  }
}

// ---------------------------------------------------------------------------
// combine_ln: quadrant combine (bf16 u,v) + xb residual (bf16) + row LayerNorm.
// Block (k,z) owns FULL rows k and 4096-k; writes out1 bf16 directly.
// u/v row stride is 2176 (padded M of GEMM_uv).
// ---------------------------------------------------------------------------
__global__ __launch_bounds__(256) void combine_ln(
    const unsigned short* __restrict__ u, const unsigned short* __restrict__ v,
    const unsigned short* __restrict__ xb, const float* __restrict__ gamma,
    const float* __restrict__ beta, unsigned short* __restrict__ o1b) {
  const int k = blockIdx.x;            // 0..2048
  const int z = blockIdx.y;            // 0..7
  const long ub = ((long)z * 2176 + k) * 512;
  const long base = (long)z * 4096L * 768;
  const long rowA = base + (long)k * 768;
  const long rowB = base + (long)(4096 - k) * 768;
  const bool doRowB = (k != 0) && (k != 2048);
  const int t = threadIdx.x;

  float vA0[2], vA1[2], vB0[2], vB1[2];
  float sA = 0.f, qA = 0.f, sB = 0.f, qB = 0.f;
#pragma unroll
  for (int it = 0; it < 2; ++it) {
    const int d = t + it * 256;
    if (d <= 384) {
      const float uu = b2f(u[ub + d]);
      const float vv = b2f(v[ub + d]);
      const float a1 = uu - vv;
      const float a2 = uu + vv;
      const int dd = 768 - d;
      const bool colB = (d != 0) && (d != 384);
      float va = a1 + b2f(xb[rowA + d]);
      vA0[it] = va; sA += va; qA += va * va;
      if (colB) { float w = a2 + b2f(xb[rowA + dd]); vA1[it] = w; sA += w; qA += w * w; }
      if (doRowB) {
        float wb = a2 + b2f(xb[rowB + d]);
        vB0[it] = wb; sB += wb; qB += wb * wb;
        if (colB) { float w2 = a1 + b2f(xb[rowB + dd]); vB1[it] = w2; sB += w2; qB += w2 * w2; }
      }
    }
  }
#pragma unroll
  for (int off = 32; off > 0; off >>= 1) {
    sA += __shfl_down(sA, off, 64); qA += __shfl_down(qA, off, 64);
    sB += __shfl_down(sB, off, 64); qB += __shfl_down(qB, off, 64);
  }
  __shared__ float red[4][4];
  if ((t & 63) == 0) {
    red[t >> 6][0] = sA; red[t >> 6][1] = qA;
    red[t >> 6][2] = sB; red[t >> 6][3] = qB;
  }
  __syncthreads();
  const float SA = red[0][0] + red[1][0] + red[2][0] + red[3][0];
  const float QA = red[0][1] + red[1][1] + red[2][1] + red[3][1];
  const float SB = red[0][2] + red[1][2] + red[2][2] + red[3][2];
  const float QB = red[0][3] + red[1][3] + red[2][3] + red[3][3];
  const float muA = SA * (1.0f / 768.0f);
  const float rsA = rsqrtf(QA * (1.0f / 768.0f) - muA * muA + 1e-6f);
  const float muB = SB * (1.0f / 768.0f);
  const float rsB = rsqrtf(QB * (1.0f / 768.0f) - muB * muB + 1e-6f);

#pragma unroll
  for (int it = 0; it < 2; ++it) {
    const int d = t + it * 256;
    if (d <= 384) {
      const int dd = 768 - d;
      const bool colB = (d != 0) && (d != 384);
      const float g0 = gamma[d], b0 = beta[d];
      o1b[rowA + d] = f2b((vA0[it] - muA) * rsA * g0 + b0);
      if (colB) o1b[rowA + dd] = f2b((vA1[it] - muA) * rsA * gamma[dd] + beta[dd]);
      if (doRowB) {
        o1b[rowB + d] = f2b((vB0[it] - muB) * rsB * g0 + b0);
        if (colB) o1b[rowB + dd] = f2b((vB1[it] - muB) * rsB * gamma[dd] + beta[dd]);
      }
    }
  }
}

// ---------------------------------------------------------------------------
// LN2: bf16 y2 in, fp32 out. One 192-thread block per row; thread t covers
// cols 4t..4t+3 (ushort4 in, float4 gamma/beta/out).
// ---------------------------------------------------------------------------
__global__ __launch_bounds__(192) void ln_row_b16(
    const unsigned short* __restrict__ in, const float* __restrict__ gamma,
    const float* __restrict__ beta, float* __restrict__ outF) {
  const long row = blockIdx.x;
  const int t = threadIdx.x;           // 0..191
  const ushort4 hv = reinterpret_cast<const ushort4*>(in + row * 768)[t];
  const float v0 = b2f(hv.x), v1 = b2f(hv.y), v2 = b2f(hv.z), v3 = b2f(hv.w);
  float s = v0 + v1 + v2 + v3;
  float q = v0 * v0 + v1 * v1 + v2 * v2 + v3 * v3;
#pragma unroll
  for (int off = 32; off > 0; off >>= 1) {
    s += __shfl_down(s, off, 64);
    q += __shfl_down(q, off, 64);
  }
  __shared__ float ss[3], sq[3];
  if ((t & 63) == 0) { ss[t >> 6] = s; sq[t >> 6] = q; }
  __syncthreads();
  const float S = ss[0] + ss[1] + ss[2];
  const float Q = sq[0] + sq[1] + sq[2];
  const float mu = S * (1.0f / 768.0f);
  const float rs = rsqrtf(Q * (1.0f / 768.0f) - mu * mu + 1e-6f);
  const float4 g4 = reinterpret_cast<const float4*>(gamma)[t];
  const float4 b4 = reinterpret_cast<const float4*>(beta)[t];
  float4 o;
  o.x = (v0 - mu) * rs * g4.x + b4.x;
  o.y = (v1 - mu) * rs * g4.y + b4.y;
  o.z = (v2 - mu) * rs * g4.z + b4.z;
  o.w = (v3 - mu) * rs * g4.w + b4.w;
  reinterpret_cast<float4*>(outF + row * 768)[t] = o;
}

// ---------------------------------------------------------------------------

extern "C" void kernel_launch(void* const* d_in, const int* in_sizes, int n_in,
                              void* d_out, int out_size, void* d_ws, size_t ws_size,
                              hipStream_t stream) {
  const float* x   = (const float*)d_in[0];   // (8,4096,768)
  const float* W1  = (const float*)d_in[1];   // (768,3072)
  const float* b1  = (const float*)d_in[2];   // (3072)
  const float* W2  = (const float*)d_in[3];   // (3072,768)
  const float* b2  = (const float*)d_in[4];   // (768)
  const float* g1  = (const float*)d_in[5];
  const float* be1 = (const float*)d_in[6];
  const float* g2  = (const float*)d_in[7];
  const float* be2 = (const float*)d_in[8];
  float* out = (float*)d_out;                 // fp32 final output (LN2 only)

  char* ws = (char*)d_ws;
  unsigned short* xb   = (unsigned short*)(ws + 0L);           //  50,331,648 (live until combine_ln)
  unsigned short* Bt1  = (unsigned short*)(ws + 50331648L);    //   1,572,864
  unsigned short* Au   = (unsigned short*)(ws + 51904512L);    //   9,469,952 (2176x2176)
  unsigned short* Av   = (unsigned short*)(ws + 61374464L);    //   9,469,952
  unsigned short* xc   = (unsigned short*)(ws + 70844416L);    //  26,738,688 (8x2176x768)
  unsigned short* xs   = (unsigned short*)(ws + 97583104L);    //  26,738,688
  unsigned short* BtU  = (unsigned short*)(ws + 124321792L);   //  17,825,792 (8x512x2176)
  unsigned short* BtV  = (unsigned short*)(ws + 142147584L);   //  17,825,792 -> ends 159,973,376
  unsigned short* u_b  = (unsigned short*)(ws + 159973376L);   //  17,825,792 (8x2176x512)
  unsigned short* v_b  = (unsigned short*)(ws + 177799168L);   //  17,825,792 -> ends 195,624,960
  unsigned short* H    = (unsigned short*)(ws + 0L);           // 201,326,592 (aliases all above; dead by GEMM3)
  unsigned short* o1b  = (unsigned short*)(ws + 201326592L);   //  50,331,648 (out1, then y2 bf16 in-place)
  unsigned short* W1t  = (unsigned short*)(ws + 251658240L);   //   4,718,592
  unsigned short* W2t  = (unsigned short*)(ws + 256376832L);   //   4,718,592
  // total ws needed: 261,095,424 bytes (~249 MiB)

  // --- prep ---
  xfold<<<dim3(2049, 8), 192, 0, stream>>>(x, xb, xc, xs);
  fill_bt1<<<3072, 256, 0, stream>>>(Bt1);
  fill_auv<<<18496, 256, 0, stream>>>(Au, Av);                  // ceil(2176*2176/256)
  transpose_f32_to_bf16<<<dim3(96, 24), 256, 0, stream>>>(W1, W1t, 768, 3072);
  transpose_f32_to_bf16<<<dim3(24, 96), 256, 0, stream>>>(W2, W2t, 3072, 768);

  // --- GEMM1 (z=0: U = xc@C_D^T; z=1: V = xs@S_D^T), packed into BtU/BtV;
  //     M=17408, N=512, K=768 -> 136x4x2 = 1088 blocks ---
  gemm128<0><<<1088, 256, 0, stream>>>(
      xc, Bt1, xs, Bt1 + 512 * 768, 768, 768, 768, 0L, 0L, 1, 136, 4, 1,
      BtU, BtV, nullptr, nullptr, 0);

  // --- GEMM_uv fused (z<8: u -> u_b; z>=8: v -> v_b); M=2176, K=2176,
  //     17x4x16 = 1088 blocks, bf16 outputs ---
  gemm128<1><<<1088, 256, 0, stream>>>(
      Au, BtU, Av, BtV, 2176, 2176, 2176,
      512L * 2176L, 2176L * 512L, 8, 17, 4, 1,
      u_b, v_b, nullptr, nullptr, 512);

  // --- combine quadrants + xb residual + LN1 -> out1 (bf16), fused ---
  combine_ln<<<dim3(2049, 8), 256, 0, stream>>>(u_b, v_b, xb, g1, be1, o1b);

  // --- GEMM3: H = gelu(out1 @ W1 + b1); NYG=12, NG=2 -> 256x12x2 = 6144 blocks ---
  gemm128<2><<<6144, 256, 0, stream>>>(
      o1b, W1t, nullptr, nullptr, 768, 768, 768, 0L, 0L, 999, 256, 12, 2,
      H, nullptr, b1, nullptr, 3072);

  // --- GEMM4: y2 = H @ W2 + b2 + out1, bf16 IN-PLACE over o1b; 256x6 = 1536 ---
  gemm128<3><<<1536, 256, 0, stream>>>(
      H, W2t, nullptr, nullptr, 3072, 3072, 3072, 0L, 0L, 999, 256, 6, 1,
      o1b, nullptr, b2, o1b, 768);

  // --- LN2: bf16 y2 -> fp32 d_out ---
  ln_row_b16<<<32768, 192, 0, stream>>>(o1b, g2, be2, out);
}

// Round 16
// 599.810 us; speedup vs baseline: 1.1020x; 1.0445x over previous
//
#include <hip/hip_runtime.h>
#include <cstdint>

// FNet block on MI355X.
//   attn = Re(FFT2(x)) via bf16 MFMA matmuls + two-axis symmetry:
//     xfold (vectorized): xb = bf16(x); xc[s']=x[s']+x[4096-s'], xs=x-x_mirror
//     GEMM1 (z=0/1): U = xc @ C_D^T, V = xs @ S_D^T, packed into BtU/BtV
//     GEMM_uv (fused, z=0..15): u (cos) / v (sin), M=2176, N=512, K=2112
//            (K trimmed: only s' 0..2048 carry data; stride stays 2176)
//     combine_ln (vectorized, full-row): out1[c] from u/v[min(c,768-c)] with
//            per-half signs + xb residual + row-LayerNorm -> bf16
//   GEMM3: H = gelu(out1 @ W1 + b1)   [fast tanh-gelu]
//   GEMM4: y2 = H @ W2 + b2 + out1, written bf16 IN-PLACE over o1b
//   LN2: bf16 y2 -> fp32 d_out (vectorized ushort4/float4).
//
// GEMM core (unchanged from rounds 9-15, verified): 128x128 tile, BK=64, 4 waves,
// single 32 KiB LDS buffer, 2 barriers/K-tile, T2 swizzle (0 bank conflicts),
// gload_lds 16B staging, XCD-gather 1D grid + N-group decode.

typedef __attribute__((ext_vector_type(8))) short short8;
typedef __attribute__((ext_vector_type(4))) float f32x4;

__device__ __forceinline__ unsigned short f2b(float f) {
  union { float f; uint32_t u; } c; c.f = f;
  uint32_t u = c.u;
  u += 0x7FFFu + ((u >> 16) & 1u);   // round-to-nearest-even
  return (unsigned short)(u >> 16);
}
__device__ __forceinline__ float b2f(unsigned short h) {
  union { uint32_t u; float f; } c; c.u = ((uint32_t)h) << 16;
  return c.f;
}

// fast GELU (tanh form), ~9 VALU. max |err vs exact erf-gelu| ~3e-3.
__device__ __forceinline__ float gelu_fast(float x) {
  float x2 = x * x;
  float inner = x * fmaf(x2, 0.0356774081f, 0.7978845608f);
  float zz = fminf(inner * 2.885390082f, 80.0f);   // exp2 arg = 2*inner*log2(e)
  float E, r;
  asm("v_exp_f32 %0, %1" : "=v"(E) : "v"(zz));
  float den = E + 1.0f;
  asm("v_rcp_f32 %0, %1" : "=v"(r) : "v"(den));
  return x * E * r;
}

// ---------------------------------------------------------------------------
// xfold (vectorized): xb = bf16(x) all rows; xc/xs = folded rows (2176, padded).
// Block (k, b), k in 0..2048; 192 threads, thread t covers cols 4t..4t+3.
// ---------------------------------------------------------------------------
__global__ __launch_bounds__(192) void xfold(
    const float* __restrict__ x, unsigned short* __restrict__ xb,
    unsigned short* __restrict__ xc, unsigned short* __restrict__ xs) {
  const int k = blockIdx.x;            // 0..2048
  const int b = blockIdx.y;            // 0..7
  const long xbase = (long)b * 4096 * 768;
  const long cbase = (long)b * 2176 * 768;
  const int t = threadIdx.x;           // 0..191

  const float4 a = reinterpret_cast<const float4*>(x + xbase + (long)k * 768)[t];
  const ushort4 ab = {f2b(a.x), f2b(a.y), f2b(a.z), f2b(a.w)};
  reinterpret_cast<ushort4*>(xb + xbase + (long)k * 768)[t] = ab;

  if (k == 0 || k == 2048) {
    reinterpret_cast<ushort4*>(xc + cbase + (long)k * 768)[t] = ab;
    reinterpret_cast<ushort4*>(xs + cbase + (long)k * 768)[t] = ushort4{0, 0, 0, 0};
  } else {
    const float4 bb = reinterpret_cast<const float4*>(x + xbase + (long)(4096 - k) * 768)[t];
    const ushort4 bbb = {f2b(bb.x), f2b(bb.y), f2b(bb.z), f2b(bb.w)};
    reinterpret_cast<ushort4*>(xb + xbase + (long)(4096 - k) * 768)[t] = bbb;
    const ushort4 cc = {f2b(a.x + bb.x), f2b(a.y + bb.y), f2b(a.z + bb.z), f2b(a.w + bb.w)};
    const ushort4 ssv = {f2b(a.x - bb.x), f2b(a.y - bb.y), f2b(a.z - bb.z), f2b(a.w - bb.w)};
    reinterpret_cast<ushort4*>(xc + cbase + (long)k * 768)[t] = cc;
    reinterpret_cast<ushort4*>(xs + cbase + (long)k * 768)[t] = ssv;
  }
  if (k >= 1 && k <= 127) {            // zero pad rows 2049..2175
    reinterpret_cast<ushort4*>(xc + cbase + (long)(2048 + k) * 768)[t] = ushort4{0, 0, 0, 0};
    reinterpret_cast<ushort4*>(xs + cbase + (long)(2048 + k) * 768)[t] = ushort4{0, 0, 0, 0};
  }
}

// Bt1: (1024 x 768). Row j<512: cos(2*pi*j*n/768); row j>=512: sin(2*pi*(j-512)*n/768).
__global__ __launch_bounds__(256) void fill_bt1(unsigned short* __restrict__ Bt1) {
  int i = blockIdx.x * 256 + threadIdx.x;          // < 1024*768
  int j = i / 768;
  int n = i - j * 768;
  int jj = j & 511;
  int m = (jj * n) % 768;
  float ang = (float)m * (6.283185307179586f / 768.0f);
  Bt1[i] = f2b((j < 512) ? cosf(ang) : sinf(ang));
}

// Au[k][s'] = cos(2*pi*k*s'/4096), Av[k][s'] = sin(...), k,s' in 0..2175.
__global__ __launch_bounds__(256) void fill_auv(
    unsigned short* __restrict__ Au, unsigned short* __restrict__ Av) {
  long i = (long)blockIdx.x * 256 + threadIdx.x;   // < 2176*2176
  if (i >= 2176L * 2176L) return;
  int k = (int)(i / 2176);
  int s = (int)(i - (long)k * 2176);
  int mm = (k * s) & 4095;
  float ang = (float)mm * (6.283185307179586f / 4096.0f);
  Au[i] = f2b(cosf(ang));
  Av[i] = f2b(sinf(ang));
}

// out[c][r] = bf16(in[r][c]); R,C multiples of 32  (for W1, W2)
__global__ __launch_bounds__(256) void transpose_f32_to_bf16(
    const float* __restrict__ in, unsigned short* __restrict__ out, int R, int C) {
  __shared__ float tile[32][33];
  const int c0 = blockIdx.x * 32;
  const int r0 = blockIdx.y * 32;
  const int tx = threadIdx.x & 31;
  const int ty = threadIdx.x >> 5;   // 0..7
#pragma unroll
  for (int i = ty; i < 32; i += 8)
    tile[i][tx] = in[(long)(r0 + i) * C + c0 + tx];
  __syncthreads();
#pragma unroll
  for (int i = ty; i < 32; i += 8)
    out[(long)(c0 + i) * R + r0 + tx] = f2b(tile[tx][i]);
}

// ---------------------------------------------------------------------------
// GEMM128: C = A (MxK row-major bf16) @ Bt^T (Bt NxK row-major bf16)
// 128x128 tile, BK=64, 256 threads (4 waves, 2x2), per-wave 64x64, acc[4][4].
// Single 32 KiB LDS buffer, 2 syncthreads/K-tile. T2 swizzle.
// 1D grid, XCD-gather remap (grid % 8 == 0) + N-GROUP decode:
//   l = (p%8)*(total/8)+p/8;
//   byg = l%NYG; bx = (l/NYG)%NX; g = (l/(NYG*NX))%NG; zz = l/(NYG*NX*NG);
//   by = g*NYG + byg.
// z>=zSplit switches operand set (A2p, Bt2p, outB2) for EPI 0 and 1.
// Epilogues:
//   0 = transpose-pack: dst[(b*512+col)*2176 + s'], b=r/2176, s'=r%2176
//   1 = bf16 z-batched store (GEMM_u / GEMM_v, z-switched)
//   2 = +bias, fast gelu, bf16 (GEMM3->H)
//   3 = +bias +bf16 resid, bf16 store IN-PLACE over residB (GEMM4->y2b)
// M,N multiples of 128; K multiple of 64 (lda/ldb may exceed K).
// ---------------------------------------------------------------------------

template <int EPI>
__global__ __launch_bounds__(256, 3) void gemm128(
    const unsigned short* __restrict__ A, const unsigned short* __restrict__ Bt,
    const unsigned short* __restrict__ A2p, const unsigned short* __restrict__ Bt2p,
    int K, int lda, int ldb, long bBatch, long oBatch, int zSplit,
    int NX, int NYG, int NG,
    unsigned short* __restrict__ outB, unsigned short* __restrict__ outB2,
    const float* __restrict__ bias, const unsigned short* __restrict__ residB,
    int ldOut) {
  __shared__ __align__(16) unsigned short As[128 * 64];   // 16 KB
  __shared__ __align__(16) unsigned short Bs[128 * 64];   // 16 KB

  const int tid = threadIdx.x;
  const int lane = tid & 63;
  const int wave = tid >> 6;         // 0..3
  const int wr = wave >> 1;          // 0..1
  const int wc = wave & 1;           // 0..1

  // ---- XCD-gather remap + N-group decode ----
  const int p = (int)blockIdx.x;
  const int l = (p & 7) * ((int)gridDim.x >> 3) + (p >> 3);
  int rem = l;
  const int byg = rem % NYG; rem /= NYG;
  const int bx  = rem % NX;  rem /= NX;
  const int g   = rem % NG;  rem /= NG;
  int zz = rem;
  const int by = g * NYG + byg;

  const unsigned short* Ax = A;
  const unsigned short* Bx = Bt;
  unsigned short* oB = outB;
  if ((EPI == 0 || EPI == 1) && zz >= zSplit) { Ax = A2p; Bx = Bt2p; oB = outB2; zz -= zSplit; }

  const unsigned short* Ab = Ax + (long)bx * 128 * lda;
  const unsigned short* Bb = Bx + (long)zz * bBatch + (long)by * 128 * ldb;

  const int NT = K >> 6;             // #K-tiles

  // Staging: linear LDS dest, T2 swizzle pre-applied to per-lane GLOBAL column.
  const int srow = lane >> 3;                      // 0..7
  const int scolE = ((lane & 7) ^ srow) << 3;      // pre-swizzled col (elems)

  const int fr = lane & 15;          // frag row within 16
  const int fkB = (lane >> 4) << 4;  // byte k-offset within 32-k half (0,16,32,48)
  const int fxor = (lane & 7) << 4;  // T2 swizzle XOR (row&7 == lane&7 for frag rows)

  f32x4 acc[4][4] = {};

  for (int t = 0; t < NT; ++t) {
    // ---- stage tile t: 16 chunks of 8 rows; wave w does chunks i*4+w ----
#pragma unroll
    for (int i_ = 0; i_ < 4; ++i_) {
      const int chunk = i_ * 4 + wave;             // wave-uniform
      const int row = chunk * 8 + srow;
      __builtin_amdgcn_global_load_lds(
          (const __attribute__((address_space(1))) void*)(Ab + (long)row * lda + (long)t * 64 + scolE),
          (__attribute__((address_space(3))) void*)(As + chunk * 512), 16, 0, 0);
      __builtin_amdgcn_global_load_lds(
          (const __attribute__((address_space(1))) void*)(Bb + (long)row * ldb + (long)t * 64 + scolE),
          (__attribute__((address_space(3))) void*)(Bs + chunk * 512), 16, 0, 0);
    }
    __syncthreads();   // drains vmcnt (gload_lds) — data visible to all waves

    const char* Ap = reinterpret_cast<const char*>(As);
    const char* Bp = reinterpret_cast<const char*>(Bs);
#pragma unroll
    for (int ks = 0; ks < 2; ++ks) {
      short8 af[4], bf[4];
#pragma unroll
      for (int mf = 0; mf < 4; ++mf) {
        const int row = wr * 64 + mf * 16 + fr;
        af[mf] = *reinterpret_cast<const short8*>(Ap + ((row * 128 + ks * 64 + fkB) ^ fxor));
      }
#pragma unroll
      for (int nf = 0; nf < 4; ++nf) {
        const int row = wc * 64 + nf * 16 + fr;
        bf[nf] = *reinterpret_cast<const short8*>(Bp + ((row * 128 + ks * 64 + fkB) ^ fxor));
      }
#pragma unroll
      for (int mf = 0; mf < 4; ++mf)
#pragma unroll
        for (int nf = 0; nf < 4; ++nf)
          acc[mf][nf] = __builtin_amdgcn_mfma_f32_16x16x32_bf16(
              af[mf], bf[nf], acc[mf][nf], 0, 0, 0);
    }
    __syncthreads();   // all waves done reading before next stage overwrites
  }

  // Epilogue. C/D layout: col = lane&15, row = (lane>>4)*4 + reg  [m89/m91]
  const long rowBase = (long)bx * 128 + wr * 64 + ((lane >> 4) << 2);
  const int colBase = by * 128 + wc * 64 + (lane & 15);
#pragma unroll
  for (int mf = 0; mf < 4; ++mf) {
#pragma unroll
    for (int nf = 0; nf < 4; ++nf) {
      const int col = colBase + nf * 16;
#pragma unroll
      for (int i = 0; i < 4; ++i) {
        const long r = rowBase + mf * 16 + i;
        float vv = acc[mf][nf][i];
        if constexpr (EPI == 0) {
          // pack: b = r/2176, s' = r%2176; dst = (b*512+col)*2176 + s'
          const int rr = (int)r;
          const int bz = rr / 2176;
          const int sp = rr - bz * 2176;
          oB[((long)(bz * 512 + col)) * 2176 + sp] = f2b(vv);
        } else if constexpr (EPI == 1) {
          oB[(long)zz * oBatch + r * (long)ldOut + col] = f2b(vv);
        } else if constexpr (EPI == 2) {
          outB[r * (long)ldOut + col] = f2b(gelu_fast(vv + bias[col]));
        } else {
          // y2 bf16 in-place over residB: same thread reads then writes idx.
          const long idx = r * (long)ldOut + col;
          outB[idx] = f2b(vv + bias[col] + b2f(residB[idx]));
        }
      }
    }
  }
}

// ---------------------------------------------------------------------------
// combine_ln (vectorized, full-row): block (k,z) computes BOTH full rows
// k and 4096-k. Thread t owns output columns c = 4t..4t+3 (192 threads).
//   m = (c <= 384) ? c : 768-c
//   rowA[c] = u[m] - v[m]  (c<=384)   /  u[m] + v[m]  (c>384)
//   rowB[c] = u[m] + v[m]  (c<=384)   /  u[m] - v[m]  (c>384)
// + xb residual, row LayerNorm, bf16 out. All accesses ushort4/float4
// (mirror half reads two overlapping aligned quads). u/v stride 2176 rows.
// ---------------------------------------------------------------------------
__global__ __launch_bounds__(192) void combine_ln(
    const unsigned short* __restrict__ u, const unsigned short* __restrict__ v,
    const unsigned short* __restrict__ xb, const float* __restrict__ gamma,
    const float* __restrict__ beta, unsigned short* __restrict__ o1b) {
  const int k = blockIdx.x;            // 0..2048
  const int z = blockIdx.y;            // 0..7
  const long ub = ((long)z * 2176 + k) * 512;
  const long base = (long)z * 4096L * 768;
  const long rowA = base + (long)k * 768;
  const long rowB = base + (long)(4096 - k) * 768;
  const bool doRowB = (k != 0) && (k != 2048);
  const int t = threadIdx.x;           // 0..191
  const int c0 = t << 2;               // 4t

  float uu[4], vv[4];
  if (t < 96) {                        // c 0..383: m = c, one aligned quad
    const ushort4 uq = *reinterpret_cast<const ushort4*>(u + ub + c0);
    const ushort4 vq = *reinterpret_cast<const ushort4*>(v + ub + c0);
    uu[0] = b2f(uq.x); uu[1] = b2f(uq.y); uu[2] = b2f(uq.z); uu[3] = b2f(uq.w);
    vv[0] = b2f(vq.x); vv[1] = b2f(vq.y); vv[2] = b2f(vq.z); vv[3] = b2f(vq.w);
  } else {                             // c >= 384: m = 768-c, two aligned quads
    const int m0 = 768 - c0;           // multiple of 4; m for j=0
    const ushort4 q1u = *reinterpret_cast<const ushort4*>(u + ub + m0 - 4);
    const ushort4 q2u = *reinterpret_cast<const ushort4*>(u + ub + m0);
    const ushort4 q1v = *reinterpret_cast<const ushort4*>(v + ub + m0 - 4);
    const ushort4 q2v = *reinterpret_cast<const ushort4*>(v + ub + m0);
    uu[0] = b2f(q2u.x); uu[1] = b2f(q1u.w); uu[2] = b2f(q1u.z); uu[3] = b2f(q1u.y);
    vv[0] = b2f(q2v.x); vv[1] = b2f(q1v.w); vv[2] = b2f(q1v.z); vv[3] = b2f(q1v.y);
  }

  const ushort4 xaq = *reinterpret_cast<const ushort4*>(xb + rowA + c0);
  const float xa[4] = {b2f(xaq.x), b2f(xaq.y), b2f(xaq.z), b2f(xaq.w)};
  float xbv[4] = {0.f, 0.f, 0.f, 0.f};
  if (doRowB) {
    const ushort4 xbq = *reinterpret_cast<const ushort4*>(xb + rowB + c0);
    xbv[0] = b2f(xbq.x); xbv[1] = b2f(xbq.y); xbv[2] = b2f(xbq.z); xbv[3] = b2f(xbq.w);
  }

  float va[4], vb[4];
  float sA = 0.f, qA = 0.f, sB = 0.f, qB = 0.f;
#pragma unroll
  for (int j = 0; j < 4; ++j) {
    const int c = c0 + j;
    const float dv = (c <= 384) ? -vv[j] : vv[j];
    va[j] = uu[j] + dv + xa[j];
    vb[j] = uu[j] - dv + xbv[j];
    sA += va[j]; qA += va[j] * va[j];
    sB += vb[j]; qB += vb[j] * vb[j];
  }
#pragma unroll
  for (int off = 32; off > 0; off >>= 1) {
    sA += __shfl_down(sA, off, 64); qA += __shfl_down(qA, off, 64);
    sB += __shfl_down(sB, off, 64); qB += __shfl_down(qB, off, 64);
  }
  __shared__ float red[3][4];
  if ((t & 63) == 0) {
    red[t >> 6][0] = sA; red[t >> 6][1] = qA;
    red[t >> 6][2] = sB; red[t >> 6][3] = qB;
  }
  __syncthreads();
  const float SA = red[0][0] + red[1][0] + red[2][0];
  const float QA = red[0][1] + red[1][1] + red[2][1];
  const float SB = red[0][2] + red[1][2] + red[2][2];
  const float QB = red[0][3] + red[1][3] + red[2][3];
  const float muA = SA * (1.0f / 768.0f);
  const float rsA = rsqrtf(QA * (1.0f / 768.0f) - muA * muA + 1e-6f);
  const float muB = SB * (1.0f / 768.0f);
  const float rsB = rsqrtf(QB * (1.0f / 768.0f) - muB * muB + 1e-6f);

  const float4 g4 = reinterpret_cast<const float4*>(gamma)[t];
  const float4 b4 = reinterpret_cast<const float4*>(beta)[t];
  ushort4 oa;
  oa.x = f2b((va[0] - muA) * rsA * g4.x + b4.x);
  oa.y = f2b((va[1] - muA) * rsA * g4.y + b4.y);
  oa.z = f2b((va[2] - muA) * rsA * g4.z + b4.z);
  oa.w = f2b((va[3] - muA) * rsA * g4.w + b4.w);
  reinterpret_cast<ushort4*>(o1b + rowA + c0)[0] = oa;
  if (doRowB) {
    ushort4 ob;
    ob.x = f2b((vb[0] - muB) * rsB * g4.x + b4.x);
    ob.y = f2b((vb[1] - muB) * rsB * g4.y + b4.y);
    ob.z = f2b((vb[2] - muB) * rsB * g4.z + b4.z);
    ob.w = f2b((vb[3] - muB) * rsB * g4.w + b4.w);
    reinterpret_cast<ushort4*>(o1b + rowB + c0)[0] = ob;
  }
}

// ---------------------------------------------------------------------------
// LN2: bf16 y2 in, fp32 out. One 192-thread block per row; thread t covers
// cols 4t..4t+3 (ushort4 in, float4 gamma/beta/out).
// ---------------------------------------------------------------------------
__global__ __launch_bounds__(192) void ln_row_b16(
    const unsigned short* __restrict__ in, const float* __restrict__ gamma,
    const float* __restrict__ beta, float* __restrict__ outF) {
  const long row = blockIdx.x;
  const int t = threadIdx.x;           // 0..191
  const ushort4 hv = reinterpret_cast<const ushort4*>(in + row * 768)[t];
  const float v0 = b2f(hv.x), v1 = b2f(hv.y), v2 = b2f(hv.z), v3 = b2f(hv.w);
  float s = v0 + v1 + v2 + v3;
  float q = v0 * v0 + v1 * v1 + v2 * v2 + v3 * v3;
#pragma unroll
  for (int off = 32; off > 0; off >>= 1) {
    s += __shfl_down(s, off, 64);
    q += __shfl_down(q, off, 64);
  }
  __shared__ float ss[3], sq[3];
  if ((t & 63) == 0) { ss[t >> 6] = s; sq[t >> 6] = q; }
  __syncthreads();
  const float S = ss[0] + ss[1] + ss[2];
  const float Q = sq[0] + sq[1] + sq[2];
  const float mu = S * (1.0f / 768.0f);
  const float rs = rsqrtf(Q * (1.0f / 768.0f) - mu * mu + 1e-6f);
  const float4 g4 = reinterpret_cast<const float4*>(gamma)[t];
  const float4 b4 = reinterpret_cast<const float4*>(beta)[t];
  float4 o;
  o.x = (v0 - mu) * rs * g4.x + b4.x;
  o.y = (v1 - mu) * rs * g4.y + b4.y;
  o.z = (v2 - mu) * rs * g4.z + b4.z;
  o.w = (v3 - mu) * rs * g4.w + b4.w;
  reinterpret_cast<float4*>(outF + row * 768)[t] = o;
}

// ---------------------------------------------------------------------------

extern "C" void kernel_launch(void* const* d_in, const int* in_sizes, int n_in,
                              void* d_out, int out_size, void* d_ws, size_t ws_size,
                              hipStream_t stream) {
  const float* x   = (const float*)d_in[0];   // (8,4096,768)
  const float* W1  = (const float*)d_in[1];   // (768,3072)
  const float* b1  = (const float*)d_in[2];   // (3072)
  const float* W2  = (const float*)d_in[3];   // (3072,768)
  const float* b2  = (const float*)d_in[4];   // (768)
  const float* g1  = (const float*)d_in[5];
  const float* be1 = (const float*)d_in[6];
  const float* g2  = (const float*)d_in[7];
  const float* be2 = (const float*)d_in[8];
  float* out = (float*)d_out;                 // fp32 final output (LN2 only)

  char* ws = (char*)d_ws;
  unsigned short* xb   = (unsigned short*)(ws + 0L);           //  50,331,648 (live until combine_ln)
  unsigned short* Bt1  = (unsigned short*)(ws + 50331648L);    //   1,572,864
  unsigned short* Au   = (unsigned short*)(ws + 51904512L);    //   9,469,952 (2176x2176)
  unsigned short* Av   = (unsigned short*)(ws + 61374464L);    //   9,469,952
  unsigned short* xc   = (unsigned short*)(ws + 70844416L);    //  26,738,688 (8x2176x768)
  unsigned short* xs   = (unsigned short*)(ws + 97583104L);    //  26,738,688
  unsigned short* BtU  = (unsigned short*)(ws + 124321792L);   //  17,825,792 (8x512x2176)
  unsigned short* BtV  = (unsigned short*)(ws + 142147584L);   //  17,825,792 -> ends 159,973,376
  unsigned short* u_b  = (unsigned short*)(ws + 159973376L);   //  17,825,792 (8x2176x512)
  unsigned short* v_b  = (unsigned short*)(ws + 177799168L);   //  17,825,792 -> ends 195,624,960
  unsigned short* H    = (unsigned short*)(ws + 0L);           // 201,326,592 (aliases all above; dead by GEMM3)
  unsigned short* o1b  = (unsigned short*)(ws + 201326592L);   //  50,331,648 (out1, then y2 bf16 in-place)
  unsigned short* W1t  = (unsigned short*)(ws + 251658240L);   //   4,718,592
  unsigned short* W2t  = (unsigned short*)(ws + 256376832L);   //   4,718,592
  // total ws needed: 261,095,424 bytes (~249 MiB)

  // --- prep ---
  xfold<<<dim3(2049, 8), 192, 0, stream>>>(x, xb, xc, xs);
  fill_bt1<<<3072, 256, 0, stream>>>(Bt1);
  fill_auv<<<18496, 256, 0, stream>>>(Au, Av);                  // ceil(2176*2176/256)
  transpose_f32_to_bf16<<<dim3(96, 24), 256, 0, stream>>>(W1, W1t, 768, 3072);
  transpose_f32_to_bf16<<<dim3(24, 96), 256, 0, stream>>>(W2, W2t, 3072, 768);

  // --- GEMM1 (z=0: U = xc@C_D^T; z=1: V = xs@S_D^T), packed into BtU/BtV;
  //     M=17408, N=512, K=768 -> 136x4x2 = 1088 blocks ---
  gemm128<0><<<1088, 256, 0, stream>>>(
      xc, Bt1, xs, Bt1 + 512 * 768, 768, 768, 768, 0L, 0L, 1, 136, 4, 1,
      BtU, BtV, nullptr, nullptr, 0);

  // --- GEMM_uv fused (z<8: u -> u_b; z>=8: v -> v_b); M=2176, K=2112 (trimmed,
  //     strides 2176); 17x4x16 = 1088 blocks, bf16 outputs ---
  gemm128<1><<<1088, 256, 0, stream>>>(
      Au, BtU, Av, BtV, 2112, 2176, 2176,
      512L * 2176L, 2176L * 512L, 8, 17, 4, 1,
      u_b, v_b, nullptr, nullptr, 512);

  // --- combine quadrants + xb residual + LN1 -> out1 (bf16), fused/vectorized ---
  combine_ln<<<dim3(2049, 8), 192, 0, stream>>>(u_b, v_b, xb, g1, be1, o1b);

  // --- GEMM3: H = gelu(out1 @ W1 + b1); NYG=12, NG=2 -> 256x12x2 = 6144 blocks ---
  gemm128<2><<<6144, 256, 0, stream>>>(
      o1b, W1t, nullptr, nullptr, 768, 768, 768, 0L, 0L, 999, 256, 12, 2,
      H, nullptr, b1, nullptr, 3072);

  // --- GEMM4: y2 = H @ W2 + b2 + out1, bf16 IN-PLACE over o1b; 256x6 = 1536 ---
  gemm128<3><<<1536, 256, 0, stream>>>(
      H, W2t, nullptr, nullptr, 3072, 3072, 3072, 0L, 0L, 999, 256, 6, 1,
      o1b, nullptr, b2, o1b, 768);

  // --- LN2: bf16 y2 -> fp32 d_out ---
  ln_row_b16<<<32768, 192, 0, stream>>>(o1b, g2, be2, out);
}